// Round 8
// baseline (474.718 us; speedup 1.0000x reference)
//
#include <hip/hip_runtime.h>
#include <math.h>

#define NN 100000
#define EE 1600000
#define IND 256
#define SLOPE 0.2f

#define BUKBITS 9
#define BUKSZ 512            // nodes per bucket
#define NBUK 196             // ceil(NN/512)
#define CAP 8960             // bucket capacity: mean 8192 + 8*sigma(90)
#define CHUNK 4096           // edges per bin block
#define BINBLK 391           // ceil(EE/CHUNK)
#define NODEBLK 391          // ceil(NN/256)
#define SKW 1024             // semantic_key: waves per m-slice (256 blk x 4)

typedef float f4 __attribute__((ext_vector_type(4)));  // native vec for nt builtins

// ---------------------------------------------------------------------------
// V matrices: alpha = h @ V,  V[et][k][h] = sum_c W[et][k][h*8+c] * a[et][h][c]
// ---------------------------------------------------------------------------
__global__ __launch_bounds__(512) void prep_V(
    const float* __restrict__ Ws, const float* __restrict__ as_,
    const float* __restrict__ Wd, const float* __restrict__ ad_,
    float* __restrict__ Vs, float* __restrict__ Vd) {
  int t = threadIdx.x;             // 0..511
  int half = t >> 8;
  int r = t & 255;
  int et = r >> 6, k = (r >> 3) & 7, hh = r & 7;
  const float* W = half ? Wd : Ws;
  const float* a = half ? ad_ : as_;
  float acc = 0.f;
#pragma unroll
  for (int c = 0; c < 8; ++c)
    acc += W[et * 512 + k * 64 + hh * 8 + c] * a[et * 64 + hh * 8 + c];
  (half ? Vd : Vs)[et * 64 + k * 8 + hh] = acc;
}

// ---------------------------------------------------------------------------
// FC: h[row][0..7] = x[row] @ Wfc + b.  Thread-per-row streaming GEMM (N=8).
// ---------------------------------------------------------------------------
__global__ __launch_bounds__(256) void fc_kernel(
    const float* __restrict__ xa, const float* __restrict__ xp,
    const float* __restrict__ Wa, const float* __restrict__ ba,
    const float* __restrict__ Wp, const float* __restrict__ bp,
    float* __restrict__ h) {
  __shared__ float sW[IND * 8];    // 8 KB
  __shared__ float sB[8];
  int bid = blockIdx.x;
  int type = bid >= NODEBLK;
  int lrow = (type ? bid - NODEBLK : bid) * 256 + threadIdx.x;
  const float* W = type ? Wp : Wa;
  const float* bb = type ? bp : ba;
  for (int i = threadIdx.x; i < IND * 8; i += 256) sW[i] = W[i];
  if (threadIdx.x < 8) sB[threadIdx.x] = bb[threadIdx.x];
  __syncthreads();
  if (lrow >= NN) return;
  const float* x = (type ? xp : xa) + (size_t)lrow * IND;
  float acc[8];
#pragma unroll
  for (int c = 0; c < 8; ++c) acc[c] = sB[c];
#pragma unroll 4
  for (int k4 = 0; k4 < IND / 4; ++k4) {
    float4 xv = ((const float4*)x)[k4];
    float xk[4] = {xv.x, xv.y, xv.z, xv.w};
#pragma unroll
    for (int kk = 0; kk < 4; ++kk) {
      const float* wr = &sW[(k4 * 4 + kk) * 8];
#pragma unroll
      for (int c = 0; c < 8; ++c) acc[c] = fmaf(xk[kk], wr[c], acc[c]);
    }
  }
  size_t row = (size_t)type * NN + lrow;
  *(float4*)(h + row * 8) = make_float4(acc[0], acc[1], acc[2], acc[3]);
  *(float4*)(h + row * 8 + 4) = make_float4(acc[4], acc[5], acc[6], acc[7]);
}

// ---------------------------------------------------------------------------
// Phase 1: bucket binning. nt loads on the 51MB edge stream so it doesn't
// evict h (gat_pull's gather hot set) from L2.
// ---------------------------------------------------------------------------
__global__ __launch_bounds__(256) void bin_kernel(
    const int* __restrict__ e0, const int* __restrict__ e1,
    const int* __restrict__ e2, const int* __restrict__ e3,
    int* __restrict__ gcur, int* __restrict__ edge_src) {
  __shared__ int s_pack[CHUNK];
  __shared__ unsigned char s_buk[CHUNK];
  __shared__ int s_hist[NBUK], s_base[NBUK], s_cur[NBUK];
  int et = blockIdx.y;
  const int* ei = et == 0 ? e0 : et == 1 ? e1 : et == 2 ? e2 : e3;
  int t = threadIdx.x;
  for (int b = t; b < NBUK; b += 256) { s_hist[b] = 0; s_cur[b] = 0; }
  __syncthreads();
  int base = blockIdx.x * CHUNK;
#pragma unroll
  for (int r = 0; r < CHUNK / 256; ++r) {
    int i = r * 256 + t;
    int e = base + i;
    int bk = 255;
    if (e < EE) {
      int s = __builtin_nontemporal_load(ei + e);
      int d = __builtin_nontemporal_load(ei + EE + e);
      s_pack[i] = s | ((d & (BUKSZ - 1)) << 17);
      bk = d >> BUKBITS;
      atomicAdd(&s_hist[bk], 1);
    }
    s_buk[i] = (unsigned char)bk;
  }
  __syncthreads();
  for (int b = t; b < NBUK; b += 256)
    s_base[b] = atomicAdd(&gcur[et * NBUK + b], s_hist[b]);
  __syncthreads();
#pragma unroll
  for (int r = 0; r < CHUNK / 256; ++r) {
    int i = r * 256 + t;
    int bk = s_buk[i];
    if (bk != 255) {
      int pos = s_base[bk] + atomicAdd(&s_cur[bk], 1);
      if (pos < CAP)  // statistically impossible overflow guard
        edge_src[(size_t)(et * NBUK + bk) * CAP + pos] = s_pack[i];
    }
  }
}

// ---------------------------------------------------------------------------
// Phase 2: per-bucket CSR (LDS hist + scan + in-place scatter, dense writes).
// ---------------------------------------------------------------------------
__global__ __launch_bounds__(256) void csr_kernel(
    const int* __restrict__ gcur, int* __restrict__ edge_src,
    int* __restrict__ counts, int* __restrict__ rowptr) {
  __shared__ int s_data[CAP];
  __shared__ int s_hist[BUKSZ], s_off[BUKSZ], s_part[256];
  int buk = blockIdx.x, et = blockIdx.y, t = threadIdx.x;
  int bsz = gcur[et * NBUK + buk];
  if (bsz > CAP) bsz = CAP;
  int ebase = (et * NBUK + buk) * CAP;
  for (int j = t; j < BUKSZ; j += 256) s_hist[j] = 0;
  __syncthreads();
  for (int i = t; i < bsz; i += 256) {
    int v = __builtin_nontemporal_load(edge_src + ebase + i);
    s_data[i] = v;
    atomicAdd(&s_hist[v >> 17], 1);
  }
  __syncthreads();
  int b2 = t * 2;
  int a0 = s_hist[b2], a1 = s_hist[b2 + 1];
  int tot = a0 + a1;
  s_part[t] = tot;
  __syncthreads();
#pragma unroll
  for (int off = 1; off < 256; off <<= 1) {
    int v = (t >= off) ? s_part[t - off] : 0;
    __syncthreads();
    s_part[t] += v;
    __syncthreads();
  }
  int ex = s_part[t] - tot;
  s_off[b2] = ex;
  s_off[b2 + 1] = ex + a0;
  __syncthreads();
  for (int j = t; j < BUKSZ; j += 256) {
    int node = buk * BUKSZ + j;
    if (node < NN) {
      counts[(size_t)et * NN + node] = s_hist[j];
      rowptr[(size_t)et * NN + node] = ebase + s_off[j];
    }
  }
  __syncthreads();
  for (int i = t; i < bsz; i += 256) {
    int v = s_data[i];
    int pos = atomicAdd(&s_off[v >> 17], 1);
    edge_src[ebase + pos] = v & 0x1FFFF;
  }
}

// ---------------------------------------------------------------------------
// GAT pull edge step (shared by main unrolled loop and tail).
// ---------------------------------------------------------------------------
__device__ __forceinline__ void gat_edge(
    const f4& a0, const f4& a1, const float* __restrict__ Vse,
    const float ad[8], float g[64], float z[8]) {
  float hs[8] = {a0.x, a0.y, a0.z, a0.w, a1.x, a1.y, a1.z, a1.w};
#pragma unroll
  for (int hh = 0; hh < 8; ++hh) {
    float e = ad[hh];
#pragma unroll
    for (int k = 0; k < 8; ++k) e = fmaf(hs[k], Vse[k * 8 + hh], e);
    e = e > 0.f ? e : SLOPE * e;
    float w = __expf(e);
    z[hh] += w;
#pragma unroll
    for (int k = 0; k < 8; ++k) g[hh * 8 + k] = fmaf(w, hs[k], g[hh * 8 + k]);
  }
}

// ---------------------------------------------------------------------------
// GAT pull: thread per dst node, 4-edge gather batches (8 loads in flight),
// nt stores for out_et + nt loads for edge_src so the h slab stays L2-hot.
// ---------------------------------------------------------------------------
__global__ __launch_bounds__(256) void gat_pull(
    const float* __restrict__ h,
    const int* __restrict__ rowptr, const int* __restrict__ counts,
    const int* __restrict__ edge_src,
    const float* __restrict__ Wsrc_all, const float* __restrict__ Vs,
    const float* __restrict__ Vd,
    const float* __restrict__ bias_all, float* __restrict__ out_et) {
  int b = blockIdx.x;
  int xcd = b & 7;
  int g_ = xcd >> 2;                      // src type this XCD owns
  int sid = (b >> 3) * 4 + (xcd & 3);     // 0..783
  if (sid >= 2 * NODEBLK) return;
  int et = (sid < NODEBLK) ? g_ : g_ + 2; // a:{0,2}  p:{1,3}
  int nb = (sid < NODEBLK) ? sid : sid - NODEBLK;
  int n = nb * 256 + threadIdx.x;
  if (n >= NN) return;
  int st = et & 1;                           // src type: 0=a,1=p
  int dt = (et & 1) ^ (et < 2 ? 1 : 0);      // dst type
  const float* hsrc = h + (size_t)st * NN * 8;
  const float* hdst = h + (size_t)dt * NN * 8;
  const float* Ws = Wsrc_all + et * 512;
  const float* Vse = Vs + et * 64;
  const float* Vde = Vd + et * 64;
  const float* bs = bias_all + et * 64;

  f4 hd0 = *(const f4*)(hdst + (size_t)n * 8);
  f4 hd1 = *(const f4*)(hdst + (size_t)n * 8 + 4);
  float hd[8] = {hd0.x, hd0.y, hd0.z, hd0.w, hd1.x, hd1.y, hd1.z, hd1.w};
  float ad[8];
#pragma unroll
  for (int hh = 0; hh < 8; ++hh) {
    float acc = 0.f;
#pragma unroll
    for (int k = 0; k < 8; ++k) acc = fmaf(hd[k], Vde[k * 8 + hh], acc);
    ad[hh] = acc;
  }
  float g[64];
  float z[8];
#pragma unroll
  for (int i = 0; i < 64; ++i) g[i] = 0.f;
#pragma unroll
  for (int hh = 0; hh < 8; ++hh) z[hh] = 0.f;

  int start = rowptr[(size_t)et * NN + n];
  int deg = counts[(size_t)et * NN + n];
  const int* es = edge_src + start;
  int i = 0;
#pragma unroll 1
  for (; i + 4 <= deg; i += 4) {
    int s0 = __builtin_nontemporal_load(es + i);
    int s1 = __builtin_nontemporal_load(es + i + 1);
    int s2 = __builtin_nontemporal_load(es + i + 2);
    int s3 = __builtin_nontemporal_load(es + i + 3);
    f4 a0 = *(const f4*)(hsrc + (size_t)s0 * 8);
    f4 a1 = *(const f4*)(hsrc + (size_t)s0 * 8 + 4);
    f4 b0 = *(const f4*)(hsrc + (size_t)s1 * 8);
    f4 b1 = *(const f4*)(hsrc + (size_t)s1 * 8 + 4);
    f4 c0 = *(const f4*)(hsrc + (size_t)s2 * 8);
    f4 c1 = *(const f4*)(hsrc + (size_t)s2 * 8 + 4);
    f4 d0 = *(const f4*)(hsrc + (size_t)s3 * 8);
    f4 d1 = *(const f4*)(hsrc + (size_t)s3 * 8 + 4);
    gat_edge(a0, a1, Vse, ad, g, z);
    gat_edge(b0, b1, Vse, ad, g, z);
    gat_edge(c0, c1, Vse, ad, g, z);
    gat_edge(d0, d1, Vse, ad, g, z);
  }
#pragma unroll 1
  for (; i < deg; ++i) {
    int s = __builtin_nontemporal_load(es + i);
    f4 a0 = *(const f4*)(hsrc + (size_t)s * 8);
    f4 a1 = *(const f4*)(hsrc + (size_t)s * 8 + 4);
    gat_edge(a0, a1, Vse, ad, g, z);
  }

  float* op = out_et + ((size_t)et * NN + n) * 64;
#pragma unroll
  for (int hh = 0; hh < 8; ++hh) {
    float rz = 1.f / (z[hh] + 1e-16f);
    float o[8];
#pragma unroll
    for (int c = 0; c < 8; ++c) {
      float acc = 0.f;
#pragma unroll
      for (int k = 0; k < 8; ++k)
        acc = fmaf(g[hh * 8 + k], Ws[k * 64 + hh * 8 + c], acc);
      o[c] = acc * rz + bs[hh * 8 + c];
    }
    f4 v0 = {o[0], o[1], o[2], o[3]};
    f4 v1 = {o[4], o[5], o[6], o[7]};
    __builtin_nontemporal_store(v0, (f4*)(op + hh * 8));
    __builtin_nontemporal_store(v1, (f4*)(op + hh * 8 + 4));
  }
}

// ---------------------------------------------------------------------------
// Semantic attention keys: key[m][j] = sum_n tanh(out_et[m][n] @ Wk + bk)[j]
// Lane = output column j; wave = node (row loads wave-uniform). nt loads:
// the 102MB out_et stream is read-once.
// ---------------------------------------------------------------------------
__global__ __launch_bounds__(256) void semantic_key(
    const float* __restrict__ out_et, const float* __restrict__ Wk,
    const float* __restrict__ bk, float* __restrict__ key) {
  __shared__ float s_red[256];
  int m = blockIdx.y;
  int lane = threadIdx.x & 63;
  float wcol[64];
#pragma unroll
  for (int k = 0; k < 64; ++k) wcol[k] = Wk[k * 64 + lane];
  float bj = bk[lane];
  float ka = 0.f;
  const float* base = out_et + (size_t)m * NN * 64;
  int gw = blockIdx.x * 4 + (threadIdx.x >> 6);
  for (int n = gw; n < NN; n += SKW) {
    int nu = __builtin_amdgcn_readfirstlane(n);
    const float* row = base + (size_t)nu * 64;
    float a0 = bj, a1 = 0.f, a2 = 0.f, a3 = 0.f;
#pragma unroll
    for (int k4 = 0; k4 < 16; ++k4) {
      f4 r = __builtin_nontemporal_load((const f4*)(row + k4 * 4));
      a0 = fmaf(r.x, wcol[k4 * 4 + 0], a0);
      a1 = fmaf(r.y, wcol[k4 * 4 + 1], a1);
      a2 = fmaf(r.z, wcol[k4 * 4 + 2], a2);
      a3 = fmaf(r.w, wcol[k4 * 4 + 3], a3);
    }
    float x = (a0 + a1) + (a2 + a3);
    float t = 1.f - 2.f / (__expf(2.f * x) + 1.f);  // tanh
    ka += t;
  }
  s_red[threadIdx.x] = ka;
  __syncthreads();
  if (threadIdx.x < 64) {
    float v = s_red[lane] + s_red[64 + lane] + s_red[128 + lane] +
              s_red[192 + lane];
    atomicAdd(&key[m * 64 + lane], v);
  }
}

// ---------------------------------------------------------------------------
// Scores: softmax over each node-type's pair of edge types.
// ---------------------------------------------------------------------------
__global__ __launch_bounds__(64) void scores_k(
    const float* __restrict__ key, const float* __restrict__ q,
    float* __restrict__ wsc) {
  int l = threadIdx.x;
  float qv = q[l];
  float d[4];
#pragma unroll
  for (int m = 0; m < 4; ++m) {
    float p = qv * key[m * 64 + l];
#pragma unroll
    for (int off = 32; off; off >>= 1) p += __shfl_xor(p, off, 64);
    d[m] = p * (1.0f / NN);  // mean over nodes
  }
  if (l == 0) {
    {
      float mx = fmaxf(d[1], d[2]);
      float e1 = __expf(d[1] - mx), e2 = __expf(d[2] - mx);
      float inv = 1.f / (e1 + e2);
      wsc[1] = e1 * inv;
      wsc[2] = e2 * inv;
    }
    {
      float mx = fmaxf(d[0], d[3]);
      float e0 = __expf(d[0] - mx), e3 = __expf(d[3] - mx);
      float inv = 1.f / (e0 + e3);
      wsc[0] = e0 * inv;
      wsc[3] = e3 * inv;
    }
  }
}

__global__ __launch_bounds__(256) void combine_kernel(
    const float* __restrict__ out_et, const float* __restrict__ wsc,
    float* __restrict__ out) {
  size_t i4 = (size_t)blockIdx.x * 256 + threadIdx.x;  // float4 index over [2][N][16]
  if (i4 >= (size_t)2 * NN * 16) return;
  int type = i4 >= (size_t)NN * 16;
  size_t r4 = type ? i4 - (size_t)NN * 16 : i4;
  int m0 = type ? 0 : 1;
  int m1 = type ? 3 : 2;
  float s0 = wsc[m0], s1 = wsc[m1];
  f4 a = __builtin_nontemporal_load((const f4*)out_et + (size_t)m0 * NN * 16 + r4);
  f4 b = __builtin_nontemporal_load((const f4*)out_et + (size_t)m1 * NN * 16 + r4);
  f4 o;
  o.x = s0 * a.x + s1 * b.x;
  o.y = s0 * a.y + s1 * b.y;
  o.z = s0 * a.z + s1 * b.z;
  o.w = s0 * a.w + s1 * b.w;
  __builtin_nontemporal_store(o, (f4*)out + i4);
}

// ---------------------------------------------------------------------------
extern "C" void kernel_launch(void* const* d_in, const int* in_sizes, int n_in,
                              void* d_out, int out_size, void* d_ws,
                              size_t ws_size, hipStream_t stream) {
  const float* x_a = (const float*)d_in[0];
  const float* x_p = (const float*)d_in[1];
  const int* ei0 = (const int*)d_in[2];   // a->p
  const int* ei1 = (const int*)d_in[3];   // p->a
  const int* ei2 = (const int*)d_in[4];   // a->a
  const int* ei3 = (const int*)d_in[5];   // p->p
  const float* Wfa = (const float*)d_in[6];
  const float* bfa = (const float*)d_in[7];
  const float* Wfp = (const float*)d_in[8];
  const float* bfp = (const float*)d_in[9];
  const float* gWs = (const float*)d_in[10];
  const float* gWd = (const float*)d_in[11];
  const float* gas = (const float*)d_in[12];
  const float* gad = (const float*)d_in[13];
  const float* gb = (const float*)d_in[14];
  const float* Wk = (const float*)d_in[15];
  const float* bk = (const float*)d_in[16];
  const float* q = (const float*)d_in[17];
  float* out = (float*)d_out;
  (void)in_sizes; (void)n_in; (void)out_size; (void)ws_size;

  float* ws = (float*)d_ws;
  float* h = ws;                                     // 2*N*8
  float* out_et = h + (size_t)2 * NN * 8;            // 4*N*64
  float* Vs = out_et + (size_t)4 * NN * 64;          // 256
  float* Vd = Vs + 256;                              // 256
  float* key = Vd + 256;                             // 256
  float* wsc = key + 256;                            // 8 (4 used)
  int* counts = (int*)(wsc + 8);                     // 4*N
  int* rowptr = counts + (size_t)4 * NN;             // 4*N
  int* gcur = rowptr + (size_t)4 * NN;               // 4*NBUK (pad 1024)
  int* edge_src = gcur + 1024;                       // 4*NBUK*CAP ints

  hipMemsetAsync(gcur, 0, 1024 * sizeof(int), stream);
  hipMemsetAsync(key, 0, 256 * sizeof(float), stream);

  prep_V<<<1, 512, 0, stream>>>(gWs, gas, gWd, gad, Vs, Vd);
  fc_kernel<<<2 * NODEBLK, 256, 0, stream>>>(x_a, x_p, Wfa, bfa, Wfp, bfp, h);
  bin_kernel<<<dim3(BINBLK, 4), 256, 0, stream>>>(ei0, ei1, ei2, ei3, gcur, edge_src);
  csr_kernel<<<dim3(NBUK, 4), 256, 0, stream>>>(gcur, edge_src, counts, rowptr);
  gat_pull<<<1568, 256, 0, stream>>>(h, rowptr, counts, edge_src,
                                     gWs, Vs, Vd, gb, out_et);
  semantic_key<<<dim3(256, 4), 256, 0, stream>>>(out_et, Wk, bk, key);
  scores_k<<<1, 64, 0, stream>>>(key, q, wsc);
  combine_kernel<<<(2 * NN * 16 + 255) / 256, 256, 0, stream>>>(out_et, wsc, out);
}

// Round 9
// 448.133 us; speedup vs baseline: 1.0593x; 1.0593x over previous
//
#include <hip/hip_runtime.h>
#include <math.h>

#define NN 100000
#define EE 1600000
#define IND 256
#define SLOPE 0.2f

#define BUKBITS 9
#define BUKSZ 512            // nodes per bucket
#define NBUK 196             // ceil(NN/512)
#define CAP 8960             // bucket capacity: mean 8192 + 8*sigma(90)
#define CHUNK 4096           // edges per bin block
#define BINBLK 391           // ceil(EE/CHUNK)
#define NODEBLK 391          // ceil(NN/256)
#define SKW 1024             // semantic_key: waves per m-slice (256 blk x 4)

typedef float f4 __attribute__((ext_vector_type(4)));  // native vec for nt builtins

// ---------------------------------------------------------------------------
// V matrices: alpha = h @ V,  V[et][k][h] = sum_c W[et][k][h*8+c] * a[et][h][c]
// ---------------------------------------------------------------------------
__global__ __launch_bounds__(512) void prep_V(
    const float* __restrict__ Ws, const float* __restrict__ as_,
    const float* __restrict__ Wd, const float* __restrict__ ad_,
    float* __restrict__ Vs, float* __restrict__ Vd) {
  int t = threadIdx.x;             // 0..511
  int half = t >> 8;
  int r = t & 255;
  int et = r >> 6, k = (r >> 3) & 7, hh = r & 7;
  const float* W = half ? Wd : Ws;
  const float* a = half ? ad_ : as_;
  float acc = 0.f;
#pragma unroll
  for (int c = 0; c < 8; ++c)
    acc += W[et * 512 + k * 64 + hh * 8 + c] * a[et * 64 + hh * 8 + c];
  (half ? Vd : Vs)[et * 64 + k * 8 + hh] = acc;
}

// ---------------------------------------------------------------------------
// FC: h[row][0..7] = x[row] @ Wfc + b.  Thread-per-row streaming GEMM (N=8).
// ---------------------------------------------------------------------------
__global__ __launch_bounds__(256) void fc_kernel(
    const float* __restrict__ xa, const float* __restrict__ xp,
    const float* __restrict__ Wa, const float* __restrict__ ba,
    const float* __restrict__ Wp, const float* __restrict__ bp,
    float* __restrict__ h) {
  __shared__ float sW[IND * 8];    // 8 KB
  __shared__ float sB[8];
  int bid = blockIdx.x;
  int type = bid >= NODEBLK;
  int lrow = (type ? bid - NODEBLK : bid) * 256 + threadIdx.x;
  const float* W = type ? Wp : Wa;
  const float* bb = type ? bp : ba;
  for (int i = threadIdx.x; i < IND * 8; i += 256) sW[i] = W[i];
  if (threadIdx.x < 8) sB[threadIdx.x] = bb[threadIdx.x];
  __syncthreads();
  if (lrow >= NN) return;
  const float* x = (type ? xp : xa) + (size_t)lrow * IND;
  float acc[8];
#pragma unroll
  for (int c = 0; c < 8; ++c) acc[c] = sB[c];
#pragma unroll 4
  for (int k4 = 0; k4 < IND / 4; ++k4) {
    f4 xv = __builtin_nontemporal_load((const f4*)x + k4);  // x read-once
    float xk[4] = {xv.x, xv.y, xv.z, xv.w};
#pragma unroll
    for (int kk = 0; kk < 4; ++kk) {
      const float* wr = &sW[(k4 * 4 + kk) * 8];
#pragma unroll
      for (int c = 0; c < 8; ++c) acc[c] = fmaf(xk[kk], wr[c], acc[c]);
    }
  }
  size_t row = (size_t)type * NN + lrow;
  *(float4*)(h + row * 8) = make_float4(acc[0], acc[1], acc[2], acc[3]);
  *(float4*)(h + row * 8 + 4) = make_float4(acc[4], acc[5], acc[6], acc[7]);
}

// ---------------------------------------------------------------------------
// Phase 1: bucket binning. nt loads on the 51MB edge stream so it doesn't
// evict h (gat_pull's gather hot set) from L2.
// ---------------------------------------------------------------------------
__global__ __launch_bounds__(256) void bin_kernel(
    const int* __restrict__ e0, const int* __restrict__ e1,
    const int* __restrict__ e2, const int* __restrict__ e3,
    int* __restrict__ gcur, int* __restrict__ edge_src) {
  __shared__ int s_pack[CHUNK];
  __shared__ unsigned char s_buk[CHUNK];
  __shared__ int s_hist[NBUK], s_base[NBUK], s_cur[NBUK];
  int et = blockIdx.y;
  const int* ei = et == 0 ? e0 : et == 1 ? e1 : et == 2 ? e2 : e3;
  int t = threadIdx.x;
  for (int b = t; b < NBUK; b += 256) { s_hist[b] = 0; s_cur[b] = 0; }
  __syncthreads();
  int base = blockIdx.x * CHUNK;
#pragma unroll
  for (int r = 0; r < CHUNK / 256; ++r) {
    int i = r * 256 + t;
    int e = base + i;
    int bk = 255;
    if (e < EE) {
      int s = __builtin_nontemporal_load(ei + e);
      int d = __builtin_nontemporal_load(ei + EE + e);
      s_pack[i] = s | ((d & (BUKSZ - 1)) << 17);
      bk = d >> BUKBITS;
      atomicAdd(&s_hist[bk], 1);
    }
    s_buk[i] = (unsigned char)bk;
  }
  __syncthreads();
  for (int b = t; b < NBUK; b += 256)
    s_base[b] = atomicAdd(&gcur[et * NBUK + b], s_hist[b]);
  __syncthreads();
#pragma unroll
  for (int r = 0; r < CHUNK / 256; ++r) {
    int i = r * 256 + t;
    int bk = s_buk[i];
    if (bk != 255) {
      int pos = s_base[bk] + atomicAdd(&s_cur[bk], 1);
      if (pos < CAP)  // statistically impossible overflow guard
        edge_src[(size_t)(et * NBUK + bk) * CAP + pos] = s_pack[i];
    }
  }
}

// ---------------------------------------------------------------------------
// Phase 2: per-bucket CSR (LDS hist + scan + in-place scatter, dense writes).
// ---------------------------------------------------------------------------
__global__ __launch_bounds__(256) void csr_kernel(
    const int* __restrict__ gcur, int* __restrict__ edge_src,
    int* __restrict__ counts, int* __restrict__ rowptr) {
  __shared__ int s_data[CAP];
  __shared__ int s_hist[BUKSZ], s_off[BUKSZ], s_part[256];
  int buk = blockIdx.x, et = blockIdx.y, t = threadIdx.x;
  int bsz = gcur[et * NBUK + buk];
  if (bsz > CAP) bsz = CAP;
  int ebase = (et * NBUK + buk) * CAP;
  for (int j = t; j < BUKSZ; j += 256) s_hist[j] = 0;
  __syncthreads();
  for (int i = t; i < bsz; i += 256) {
    int v = __builtin_nontemporal_load(edge_src + ebase + i);
    s_data[i] = v;
    atomicAdd(&s_hist[v >> 17], 1);
  }
  __syncthreads();
  int b2 = t * 2;
  int a0 = s_hist[b2], a1 = s_hist[b2 + 1];
  int tot = a0 + a1;
  s_part[t] = tot;
  __syncthreads();
#pragma unroll
  for (int off = 1; off < 256; off <<= 1) {
    int v = (t >= off) ? s_part[t - off] : 0;
    __syncthreads();
    s_part[t] += v;
    __syncthreads();
  }
  int ex = s_part[t] - tot;
  s_off[b2] = ex;
  s_off[b2 + 1] = ex + a0;
  __syncthreads();
  for (int j = t; j < BUKSZ; j += 256) {
    int node = buk * BUKSZ + j;
    if (node < NN) {
      counts[(size_t)et * NN + node] = s_hist[j];
      rowptr[(size_t)et * NN + node] = ebase + s_off[j];
    }
  }
  __syncthreads();
  for (int i = t; i < bsz; i += 256) {
    int v = s_data[i];
    int pos = atomicAdd(&s_off[v >> 17], 1);
    edge_src[ebase + pos] = v & 0x1FFFF;
  }
}

// ---------------------------------------------------------------------------
// GAT pull edge step (shared by main unrolled loop and tail).
// ---------------------------------------------------------------------------
__device__ __forceinline__ void gat_edge(
    const f4& a0, const f4& a1, const float* __restrict__ Vse,
    const float ad[8], float g[64], float z[8]) {
  float hs[8] = {a0.x, a0.y, a0.z, a0.w, a1.x, a1.y, a1.z, a1.w};
#pragma unroll
  for (int hh = 0; hh < 8; ++hh) {
    float e = ad[hh];
#pragma unroll
    for (int k = 0; k < 8; ++k) e = fmaf(hs[k], Vse[k * 8 + hh], e);
    e = e > 0.f ? e : SLOPE * e;
    float w = __expf(e);
    z[hh] += w;
#pragma unroll
    for (int k = 0; k < 8; ++k) g[hh * 8 + k] = fmaf(w, hs[k], g[hh * 8 + k]);
  }
}

// ---------------------------------------------------------------------------
// GAT pull: thread per dst node, 4-edge gather batches (8 loads in flight),
// nt loads for edge_src (stream); REGULAR write-back stores for out_et
// (nt stores caused 3x write amplification -- partial-line eager eviction).
// ---------------------------------------------------------------------------
__global__ __launch_bounds__(256) void gat_pull(
    const float* __restrict__ h,
    const int* __restrict__ rowptr, const int* __restrict__ counts,
    const int* __restrict__ edge_src,
    const float* __restrict__ Wsrc_all, const float* __restrict__ Vs,
    const float* __restrict__ Vd,
    const float* __restrict__ bias_all, float* __restrict__ out_et) {
  int b = blockIdx.x;
  int xcd = b & 7;
  int g_ = xcd >> 2;                      // src type this XCD owns
  int sid = (b >> 3) * 4 + (xcd & 3);     // 0..783
  if (sid >= 2 * NODEBLK) return;
  int et = (sid < NODEBLK) ? g_ : g_ + 2; // a:{0,2}  p:{1,3}
  int nb = (sid < NODEBLK) ? sid : sid - NODEBLK;
  int n = nb * 256 + threadIdx.x;
  if (n >= NN) return;
  int st = et & 1;                           // src type: 0=a,1=p
  int dt = (et & 1) ^ (et < 2 ? 1 : 0);      // dst type
  const float* hsrc = h + (size_t)st * NN * 8;
  const float* hdst = h + (size_t)dt * NN * 8;
  const float* Ws = Wsrc_all + et * 512;
  const float* Vse = Vs + et * 64;
  const float* Vde = Vd + et * 64;
  const float* bs = bias_all + et * 64;

  f4 hd0 = *(const f4*)(hdst + (size_t)n * 8);
  f4 hd1 = *(const f4*)(hdst + (size_t)n * 8 + 4);
  float hd[8] = {hd0.x, hd0.y, hd0.z, hd0.w, hd1.x, hd1.y, hd1.z, hd1.w};
  float ad[8];
#pragma unroll
  for (int hh = 0; hh < 8; ++hh) {
    float acc = 0.f;
#pragma unroll
    for (int k = 0; k < 8; ++k) acc = fmaf(hd[k], Vde[k * 8 + hh], acc);
    ad[hh] = acc;
  }
  float g[64];
  float z[8];
#pragma unroll
  for (int i = 0; i < 64; ++i) g[i] = 0.f;
#pragma unroll
  for (int hh = 0; hh < 8; ++hh) z[hh] = 0.f;

  int start = rowptr[(size_t)et * NN + n];
  int deg = counts[(size_t)et * NN + n];
  const int* es = edge_src + start;
  int i = 0;
#pragma unroll 1
  for (; i + 4 <= deg; i += 4) {
    int s0 = __builtin_nontemporal_load(es + i);
    int s1 = __builtin_nontemporal_load(es + i + 1);
    int s2 = __builtin_nontemporal_load(es + i + 2);
    int s3 = __builtin_nontemporal_load(es + i + 3);
    f4 a0 = *(const f4*)(hsrc + (size_t)s0 * 8);
    f4 a1 = *(const f4*)(hsrc + (size_t)s0 * 8 + 4);
    f4 b0 = *(const f4*)(hsrc + (size_t)s1 * 8);
    f4 b1 = *(const f4*)(hsrc + (size_t)s1 * 8 + 4);
    f4 c0 = *(const f4*)(hsrc + (size_t)s2 * 8);
    f4 c1 = *(const f4*)(hsrc + (size_t)s2 * 8 + 4);
    f4 d0 = *(const f4*)(hsrc + (size_t)s3 * 8);
    f4 d1 = *(const f4*)(hsrc + (size_t)s3 * 8 + 4);
    gat_edge(a0, a1, Vse, ad, g, z);
    gat_edge(b0, b1, Vse, ad, g, z);
    gat_edge(c0, c1, Vse, ad, g, z);
    gat_edge(d0, d1, Vse, ad, g, z);
  }
#pragma unroll 1
  for (; i < deg; ++i) {
    int s = __builtin_nontemporal_load(es + i);
    f4 a0 = *(const f4*)(hsrc + (size_t)s * 8);
    f4 a1 = *(const f4*)(hsrc + (size_t)s * 8 + 4);
    gat_edge(a0, a1, Vse, ad, g, z);
  }

  float* op = out_et + ((size_t)et * NN + n) * 64;
#pragma unroll
  for (int hh = 0; hh < 8; ++hh) {
    float rz = 1.f / (z[hh] + 1e-16f);
    float o[8];
#pragma unroll
    for (int c = 0; c < 8; ++c) {
      float acc = 0.f;
#pragma unroll
      for (int k = 0; k < 8; ++k)
        acc = fmaf(g[hh * 8 + k], Ws[k * 64 + hh * 8 + c], acc);
      o[c] = acc * rz + bs[hh * 8 + c];
    }
    *(float4*)(op + hh * 8) = make_float4(o[0], o[1], o[2], o[3]);
    *(float4*)(op + hh * 8 + 4) = make_float4(o[4], o[5], o[6], o[7]);
  }
}

// ---------------------------------------------------------------------------
// Semantic attention keys: key[m][j] = sum_n tanh(out_et[m][n] @ Wk + bk)[j]
// Lane = output column j; wave = node (row loads wave-uniform). nt loads:
// the 102MB out_et stream is read-once.
// ---------------------------------------------------------------------------
__global__ __launch_bounds__(256) void semantic_key(
    const float* __restrict__ out_et, const float* __restrict__ Wk,
    const float* __restrict__ bk, float* __restrict__ key) {
  __shared__ float s_red[256];
  int m = blockIdx.y;
  int lane = threadIdx.x & 63;
  float wcol[64];
#pragma unroll
  for (int k = 0; k < 64; ++k) wcol[k] = Wk[k * 64 + lane];
  float bj = bk[lane];
  float ka = 0.f;
  const float* base = out_et + (size_t)m * NN * 64;
  int gw = blockIdx.x * 4 + (threadIdx.x >> 6);
  for (int n = gw; n < NN; n += SKW) {
    int nu = __builtin_amdgcn_readfirstlane(n);
    const float* row = base + (size_t)nu * 64;
    float a0 = bj, a1 = 0.f, a2 = 0.f, a3 = 0.f;
#pragma unroll
    for (int k4 = 0; k4 < 16; ++k4) {
      f4 r = __builtin_nontemporal_load((const f4*)(row + k4 * 4));
      a0 = fmaf(r.x, wcol[k4 * 4 + 0], a0);
      a1 = fmaf(r.y, wcol[k4 * 4 + 1], a1);
      a2 = fmaf(r.z, wcol[k4 * 4 + 2], a2);
      a3 = fmaf(r.w, wcol[k4 * 4 + 3], a3);
    }
    float x = (a0 + a1) + (a2 + a3);
    float t = 1.f - 2.f / (__expf(2.f * x) + 1.f);  // tanh
    ka += t;
  }
  s_red[threadIdx.x] = ka;
  __syncthreads();
  if (threadIdx.x < 64) {
    float v = s_red[lane] + s_red[64 + lane] + s_red[128 + lane] +
              s_red[192 + lane];
    atomicAdd(&key[m * 64 + lane], v);
  }
}

// ---------------------------------------------------------------------------
// Scores: softmax over each node-type's pair of edge types.
// ---------------------------------------------------------------------------
__global__ __launch_bounds__(64) void scores_k(
    const float* __restrict__ key, const float* __restrict__ q,
    float* __restrict__ wsc) {
  int l = threadIdx.x;
  float qv = q[l];
  float d[4];
#pragma unroll
  for (int m = 0; m < 4; ++m) {
    float p = qv * key[m * 64 + l];
#pragma unroll
    for (int off = 32; off; off >>= 1) p += __shfl_xor(p, off, 64);
    d[m] = p * (1.0f / NN);  // mean over nodes
  }
  if (l == 0) {
    {
      float mx = fmaxf(d[1], d[2]);
      float e1 = __expf(d[1] - mx), e2 = __expf(d[2] - mx);
      float inv = 1.f / (e1 + e2);
      wsc[1] = e1 * inv;
      wsc[2] = e2 * inv;
    }
    {
      float mx = fmaxf(d[0], d[3]);
      float e0 = __expf(d[0] - mx), e3 = __expf(d[3] - mx);
      float inv = 1.f / (e0 + e3);
      wsc[0] = e0 * inv;
      wsc[3] = e3 * inv;
    }
  }
}

__global__ __launch_bounds__(256) void combine_kernel(
    const float* __restrict__ out_et, const float* __restrict__ wsc,
    float* __restrict__ out) {
  size_t i4 = (size_t)blockIdx.x * 256 + threadIdx.x;  // float4 index over [2][N][16]
  if (i4 >= (size_t)2 * NN * 16) return;
  int type = i4 >= (size_t)NN * 16;
  size_t r4 = type ? i4 - (size_t)NN * 16 : i4;
  int m0 = type ? 0 : 1;
  int m1 = type ? 3 : 2;
  float s0 = wsc[m0], s1 = wsc[m1];
  f4 a = __builtin_nontemporal_load((const f4*)out_et + (size_t)m0 * NN * 16 + r4);
  f4 b = __builtin_nontemporal_load((const f4*)out_et + (size_t)m1 * NN * 16 + r4);
  float4 o;
  o.x = s0 * a.x + s1 * b.x;
  o.y = s0 * a.y + s1 * b.y;
  o.z = s0 * a.z + s1 * b.z;
  o.w = s0 * a.w + s1 * b.w;
  ((float4*)out)[i4] = o;
}

// ---------------------------------------------------------------------------
extern "C" void kernel_launch(void* const* d_in, const int* in_sizes, int n_in,
                              void* d_out, int out_size, void* d_ws,
                              size_t ws_size, hipStream_t stream) {
  const float* x_a = (const float*)d_in[0];
  const float* x_p = (const float*)d_in[1];
  const int* ei0 = (const int*)d_in[2];   // a->p
  const int* ei1 = (const int*)d_in[3];   // p->a
  const int* ei2 = (const int*)d_in[4];   // a->a
  const int* ei3 = (const int*)d_in[5];   // p->p
  const float* Wfa = (const float*)d_in[6];
  const float* bfa = (const float*)d_in[7];
  const float* Wfp = (const float*)d_in[8];
  const float* bfp = (const float*)d_in[9];
  const float* gWs = (const float*)d_in[10];
  const float* gWd = (const float*)d_in[11];
  const float* gas = (const float*)d_in[12];
  const float* gad = (const float*)d_in[13];
  const float* gb = (const float*)d_in[14];
  const float* Wk = (const float*)d_in[15];
  const float* bk = (const float*)d_in[16];
  const float* q = (const float*)d_in[17];
  float* out = (float*)d_out;
  (void)in_sizes; (void)n_in; (void)out_size; (void)ws_size;

  float* ws = (float*)d_ws;
  float* h = ws;                                     // 2*N*8
  float* out_et = h + (size_t)2 * NN * 8;            // 4*N*64
  float* Vs = out_et + (size_t)4 * NN * 64;          // 256
  float* Vd = Vs + 256;                              // 256
  float* key = Vd + 256;                             // 256
  float* wsc = key + 256;                            // 8 (4 used)
  int* counts = (int*)(wsc + 8);                     // 4*N
  int* rowptr = counts + (size_t)4 * NN;             // 4*N
  int* gcur = rowptr + (size_t)4 * NN;               // 4*NBUK (pad 1024)
  int* edge_src = gcur + 1024;                       // 4*NBUK*CAP ints

  hipMemsetAsync(gcur, 0, 1024 * sizeof(int), stream);
  hipMemsetAsync(key, 0, 256 * sizeof(float), stream);

  prep_V<<<1, 512, 0, stream>>>(gWs, gas, gWd, gad, Vs, Vd);
  fc_kernel<<<2 * NODEBLK, 256, 0, stream>>>(x_a, x_p, Wfa, bfa, Wfp, bfp, h);
  bin_kernel<<<dim3(BINBLK, 4), 256, 0, stream>>>(ei0, ei1, ei2, ei3, gcur, edge_src);
  csr_kernel<<<dim3(NBUK, 4), 256, 0, stream>>>(gcur, edge_src, counts, rowptr);
  gat_pull<<<1568, 256, 0, stream>>>(h, rowptr, counts, edge_src,
                                     gWs, Vs, Vd, gb, out_et);
  semantic_key<<<dim3(256, 4), 256, 0, stream>>>(out_et, Wk, bk, key);
  scores_k<<<1, 64, 0, stream>>>(key, q, wsc);
  combine_kernel<<<(2 * NN * 16 + 255) / 256, 256, 0, stream>>>(out_et, wsc, out);
}

// Round 10
// 385.959 us; speedup vs baseline: 1.2300x; 1.1611x over previous
//
#include <hip/hip_runtime.h>
#include <math.h>

#define NN 100000
#define EE 1600000
#define IND 256
#define SLOPE 0.2f

#define BUKBITS 9
#define BUKSZ 512            // nodes per bucket
#define NBUK 196             // ceil(NN/512)
#define CAP 8960             // bucket capacity: mean 8192 + 8*sigma(90)
#define CHUNK 4096           // edges per bin block
#define BINBLK 391           // ceil(EE/CHUNK)
#define NODEBLK 391          // ceil(NN/256)
#define SKW 1024             // semantic_key: waves per m-slice (256 blk x 4)

typedef float f4 __attribute__((ext_vector_type(4)));  // native vec for nt builtins

// ---------------------------------------------------------------------------
// V matrices: alpha = h @ V,  V[et][k][h] = sum_c W[et][k][h*8+c] * a[et][h][c]
// ---------------------------------------------------------------------------
__global__ __launch_bounds__(512) void prep_V(
    const float* __restrict__ Ws, const float* __restrict__ as_,
    const float* __restrict__ Wd, const float* __restrict__ ad_,
    float* __restrict__ Vs, float* __restrict__ Vd) {
  int t = threadIdx.x;             // 0..511
  int half = t >> 8;
  int r = t & 255;
  int et = r >> 6, k = (r >> 3) & 7, hh = r & 7;
  const float* W = half ? Wd : Ws;
  const float* a = half ? ad_ : as_;
  float acc = 0.f;
#pragma unroll
  for (int c = 0; c < 8; ++c)
    acc += W[et * 512 + k * 64 + hh * 8 + c] * a[et * 64 + hh * 8 + c];
  (half ? Vd : Vs)[et * 64 + k * 8 + hh] = acc;
}

// ---------------------------------------------------------------------------
// FC: h[row][0..7] = x[row] @ Wfc + b.  Thread-per-row streaming GEMM (N=8).
// REGULAR loads for x: each 64B line is consumed over 4 consecutive float4
// loads -- nt eager eviction doubled FETCH (r9: 186MB vs 100MB).
// ---------------------------------------------------------------------------
__global__ __launch_bounds__(256) void fc_kernel(
    const float* __restrict__ xa, const float* __restrict__ xp,
    const float* __restrict__ Wa, const float* __restrict__ ba,
    const float* __restrict__ Wp, const float* __restrict__ bp,
    float* __restrict__ h) {
  __shared__ float sW[IND * 8];    // 8 KB
  __shared__ float sB[8];
  int bid = blockIdx.x;
  int type = bid >= NODEBLK;
  int lrow = (type ? bid - NODEBLK : bid) * 256 + threadIdx.x;
  const float* W = type ? Wp : Wa;
  const float* bb = type ? bp : ba;
  for (int i = threadIdx.x; i < IND * 8; i += 256) sW[i] = W[i];
  if (threadIdx.x < 8) sB[threadIdx.x] = bb[threadIdx.x];
  __syncthreads();
  if (lrow >= NN) return;
  const float* x = (type ? xp : xa) + (size_t)lrow * IND;
  float acc[8];
#pragma unroll
  for (int c = 0; c < 8; ++c) acc[c] = sB[c];
#pragma unroll 4
  for (int k4 = 0; k4 < IND / 4; ++k4) {
    float4 xv = ((const float4*)x)[k4];
    float xk[4] = {xv.x, xv.y, xv.z, xv.w};
#pragma unroll
    for (int kk = 0; kk < 4; ++kk) {
      const float* wr = &sW[(k4 * 4 + kk) * 8];
#pragma unroll
      for (int c = 0; c < 8; ++c) acc[c] = fmaf(xk[kk], wr[c], acc[c]);
    }
  }
  size_t row = (size_t)type * NN + lrow;
  *(float4*)(h + row * 8) = make_float4(acc[0], acc[1], acc[2], acc[3]);
  *(float4*)(h + row * 8 + 4) = make_float4(acc[4], acc[5], acc[6], acc[7]);
}

// ---------------------------------------------------------------------------
// Phase 1: bucket binning. nt loads on the 51MB edge stream so it doesn't
// evict h (gat_pull's gather hot set) from L2. (Edge streams are consumed
// whole-line by the wave, so nt is safe here.)
// ---------------------------------------------------------------------------
__global__ __launch_bounds__(256) void bin_kernel(
    const int* __restrict__ e0, const int* __restrict__ e1,
    const int* __restrict__ e2, const int* __restrict__ e3,
    int* __restrict__ gcur, int* __restrict__ edge_src) {
  __shared__ int s_pack[CHUNK];
  __shared__ unsigned char s_buk[CHUNK];
  __shared__ int s_hist[NBUK], s_base[NBUK], s_cur[NBUK];
  int et = blockIdx.y;
  const int* ei = et == 0 ? e0 : et == 1 ? e1 : et == 2 ? e2 : e3;
  int t = threadIdx.x;
  for (int b = t; b < NBUK; b += 256) { s_hist[b] = 0; s_cur[b] = 0; }
  __syncthreads();
  int base = blockIdx.x * CHUNK;
#pragma unroll
  for (int r = 0; r < CHUNK / 256; ++r) {
    int i = r * 256 + t;
    int e = base + i;
    int bk = 255;
    if (e < EE) {
      int s = __builtin_nontemporal_load(ei + e);
      int d = __builtin_nontemporal_load(ei + EE + e);
      s_pack[i] = s | ((d & (BUKSZ - 1)) << 17);
      bk = d >> BUKBITS;
      atomicAdd(&s_hist[bk], 1);
    }
    s_buk[i] = (unsigned char)bk;
  }
  __syncthreads();
  for (int b = t; b < NBUK; b += 256)
    s_base[b] = atomicAdd(&gcur[et * NBUK + b], s_hist[b]);
  __syncthreads();
#pragma unroll
  for (int r = 0; r < CHUNK / 256; ++r) {
    int i = r * 256 + t;
    int bk = s_buk[i];
    if (bk != 255) {
      int pos = s_base[bk] + atomicAdd(&s_cur[bk], 1);
      if (pos < CAP)  // statistically impossible overflow guard
        edge_src[(size_t)(et * NBUK + bk) * CAP + pos] = s_pack[i];
    }
  }
}

// ---------------------------------------------------------------------------
// Phase 2: per-bucket CSR (LDS hist + scan + in-place scatter, dense writes).
// ---------------------------------------------------------------------------
__global__ __launch_bounds__(256) void csr_kernel(
    const int* __restrict__ gcur, int* __restrict__ edge_src,
    int* __restrict__ counts, int* __restrict__ rowptr) {
  __shared__ int s_data[CAP];
  __shared__ int s_hist[BUKSZ], s_off[BUKSZ], s_part[256];
  int buk = blockIdx.x, et = blockIdx.y, t = threadIdx.x;
  int bsz = gcur[et * NBUK + buk];
  if (bsz > CAP) bsz = CAP;
  int ebase = (et * NBUK + buk) * CAP;
  for (int j = t; j < BUKSZ; j += 256) s_hist[j] = 0;
  __syncthreads();
  for (int i = t; i < bsz; i += 256) {
    int v = __builtin_nontemporal_load(edge_src + ebase + i);
    s_data[i] = v;
    atomicAdd(&s_hist[v >> 17], 1);
  }
  __syncthreads();
  int b2 = t * 2;
  int a0 = s_hist[b2], a1 = s_hist[b2 + 1];
  int tot = a0 + a1;
  s_part[t] = tot;
  __syncthreads();
#pragma unroll
  for (int off = 1; off < 256; off <<= 1) {
    int v = (t >= off) ? s_part[t - off] : 0;
    __syncthreads();
    s_part[t] += v;
    __syncthreads();
  }
  int ex = s_part[t] - tot;
  s_off[b2] = ex;
  s_off[b2 + 1] = ex + a0;
  __syncthreads();
  for (int j = t; j < BUKSZ; j += 256) {
    int node = buk * BUKSZ + j;
    if (node < NN) {
      counts[(size_t)et * NN + node] = s_hist[j];
      rowptr[(size_t)et * NN + node] = ebase + s_off[j];
    }
  }
  __syncthreads();
  for (int i = t; i < bsz; i += 256) {
    int v = s_data[i];
    int pos = atomicAdd(&s_off[v >> 17], 1);
    edge_src[ebase + pos] = v & 0x1FFFF;
  }
}

// ---------------------------------------------------------------------------
// GAT pull edge step (shared by main unrolled loop and tail).
// ---------------------------------------------------------------------------
__device__ __forceinline__ void gat_edge(
    const f4& a0, const f4& a1, const float* __restrict__ Vse,
    const float ad[8], float g[64], float z[8]) {
  float hs[8] = {a0.x, a0.y, a0.z, a0.w, a1.x, a1.y, a1.z, a1.w};
#pragma unroll
  for (int hh = 0; hh < 8; ++hh) {
    float e = ad[hh];
#pragma unroll
    for (int k = 0; k < 8; ++k) e = fmaf(hs[k], Vse[k * 8 + hh], e);
    e = e > 0.f ? e : SLOPE * e;
    float w = __expf(e);
    z[hh] += w;
#pragma unroll
    for (int k = 0; k < 8; ++k) g[hh * 8 + k] = fmaf(w, hs[k], g[hh * 8 + k]);
  }
}

// ---------------------------------------------------------------------------
// GAT pull: thread per dst node, 4-edge gather batches (8 loads in flight),
// nt loads for edge_src (stream); REGULAR write-back stores for out_et
// (nt stores caused 3x write amplification -- partial-line eager eviction).
// ---------------------------------------------------------------------------
__global__ __launch_bounds__(256) void gat_pull(
    const float* __restrict__ h,
    const int* __restrict__ rowptr, const int* __restrict__ counts,
    const int* __restrict__ edge_src,
    const float* __restrict__ Wsrc_all, const float* __restrict__ Vs,
    const float* __restrict__ Vd,
    const float* __restrict__ bias_all, float* __restrict__ out_et) {
  int b = blockIdx.x;
  int xcd = b & 7;
  int g_ = xcd >> 2;                      // src type this XCD owns
  int sid = (b >> 3) * 4 + (xcd & 3);     // 0..783
  if (sid >= 2 * NODEBLK) return;
  int et = (sid < NODEBLK) ? g_ : g_ + 2; // a:{0,2}  p:{1,3}
  int nb = (sid < NODEBLK) ? sid : sid - NODEBLK;
  int n = nb * 256 + threadIdx.x;
  if (n >= NN) return;
  int st = et & 1;                           // src type: 0=a,1=p
  int dt = (et & 1) ^ (et < 2 ? 1 : 0);      // dst type
  const float* hsrc = h + (size_t)st * NN * 8;
  const float* hdst = h + (size_t)dt * NN * 8;
  const float* Ws = Wsrc_all + et * 512;
  const float* Vse = Vs + et * 64;
  const float* Vde = Vd + et * 64;
  const float* bs = bias_all + et * 64;

  f4 hd0 = *(const f4*)(hdst + (size_t)n * 8);
  f4 hd1 = *(const f4*)(hdst + (size_t)n * 8 + 4);
  float hd[8] = {hd0.x, hd0.y, hd0.z, hd0.w, hd1.x, hd1.y, hd1.z, hd1.w};
  float ad[8];
#pragma unroll
  for (int hh = 0; hh < 8; ++hh) {
    float acc = 0.f;
#pragma unroll
    for (int k = 0; k < 8; ++k) acc = fmaf(hd[k], Vde[k * 8 + hh], acc);
    ad[hh] = acc;
  }
  float g[64];
  float z[8];
#pragma unroll
  for (int i = 0; i < 64; ++i) g[i] = 0.f;
#pragma unroll
  for (int hh = 0; hh < 8; ++hh) z[hh] = 0.f;

  int start = rowptr[(size_t)et * NN + n];
  int deg = counts[(size_t)et * NN + n];
  const int* es = edge_src + start;
  int i = 0;
#pragma unroll 1
  for (; i + 4 <= deg; i += 4) {
    int s0 = __builtin_nontemporal_load(es + i);
    int s1 = __builtin_nontemporal_load(es + i + 1);
    int s2 = __builtin_nontemporal_load(es + i + 2);
    int s3 = __builtin_nontemporal_load(es + i + 3);
    f4 a0 = *(const f4*)(hsrc + (size_t)s0 * 8);
    f4 a1 = *(const f4*)(hsrc + (size_t)s0 * 8 + 4);
    f4 b0 = *(const f4*)(hsrc + (size_t)s1 * 8);
    f4 b1 = *(const f4*)(hsrc + (size_t)s1 * 8 + 4);
    f4 c0 = *(const f4*)(hsrc + (size_t)s2 * 8);
    f4 c1 = *(const f4*)(hsrc + (size_t)s2 * 8 + 4);
    f4 d0 = *(const f4*)(hsrc + (size_t)s3 * 8);
    f4 d1 = *(const f4*)(hsrc + (size_t)s3 * 8 + 4);
    gat_edge(a0, a1, Vse, ad, g, z);
    gat_edge(b0, b1, Vse, ad, g, z);
    gat_edge(c0, c1, Vse, ad, g, z);
    gat_edge(d0, d1, Vse, ad, g, z);
  }
#pragma unroll 1
  for (; i < deg; ++i) {
    int s = __builtin_nontemporal_load(es + i);
    f4 a0 = *(const f4*)(hsrc + (size_t)s * 8);
    f4 a1 = *(const f4*)(hsrc + (size_t)s * 8 + 4);
    gat_edge(a0, a1, Vse, ad, g, z);
  }

  float* op = out_et + ((size_t)et * NN + n) * 64;
#pragma unroll
  for (int hh = 0; hh < 8; ++hh) {
    float rz = 1.f / (z[hh] + 1e-16f);
    float o[8];
#pragma unroll
    for (int c = 0; c < 8; ++c) {
      float acc = 0.f;
#pragma unroll
      for (int k = 0; k < 8; ++k)
        acc = fmaf(g[hh * 8 + k], Ws[k * 64 + hh * 8 + c], acc);
      o[c] = acc * rz + bs[hh * 8 + c];
    }
    *(float4*)(op + hh * 8) = make_float4(o[0], o[1], o[2], o[3]);
    *(float4*)(op + hh * 8 + 4) = make_float4(o[4], o[5], o[6], o[7]);
  }
}

// ---------------------------------------------------------------------------
// Semantic attention keys: key[m][j] = sum_n tanh(out_et[m][n] @ Wk + bk)[j]
// Lane = output column j; wave = node (row loads wave-uniform). nt loads are
// safe here: the wave consumes each 64-lane row (4 lines) in full.
// ---------------------------------------------------------------------------
__global__ __launch_bounds__(256) void semantic_key(
    const float* __restrict__ out_et, const float* __restrict__ Wk,
    const float* __restrict__ bk, float* __restrict__ key) {
  __shared__ float s_red[256];
  int m = blockIdx.y;
  int lane = threadIdx.x & 63;
  float wcol[64];
#pragma unroll
  for (int k = 0; k < 64; ++k) wcol[k] = Wk[k * 64 + lane];
  float bj = bk[lane];
  float ka = 0.f;
  const float* base = out_et + (size_t)m * NN * 64;
  int gw = blockIdx.x * 4 + (threadIdx.x >> 6);
  for (int n = gw; n < NN; n += SKW) {
    int nu = __builtin_amdgcn_readfirstlane(n);
    const float* row = base + (size_t)nu * 64;
    float a0 = bj, a1 = 0.f, a2 = 0.f, a3 = 0.f;
#pragma unroll
    for (int k4 = 0; k4 < 16; ++k4) {
      f4 r = __builtin_nontemporal_load((const f4*)(row + k4 * 4));
      a0 = fmaf(r.x, wcol[k4 * 4 + 0], a0);
      a1 = fmaf(r.y, wcol[k4 * 4 + 1], a1);
      a2 = fmaf(r.z, wcol[k4 * 4 + 2], a2);
      a3 = fmaf(r.w, wcol[k4 * 4 + 3], a3);
    }
    float x = (a0 + a1) + (a2 + a3);
    float t = 1.f - 2.f / (__expf(2.f * x) + 1.f);  // tanh
    ka += t;
  }
  s_red[threadIdx.x] = ka;
  __syncthreads();
  if (threadIdx.x < 64) {
    float v = s_red[lane] + s_red[64 + lane] + s_red[128 + lane] +
              s_red[192 + lane];
    atomicAdd(&key[m * 64 + lane], v);
  }
}

// ---------------------------------------------------------------------------
// Scores: softmax over each node-type's pair of edge types.
// ---------------------------------------------------------------------------
__global__ __launch_bounds__(64) void scores_k(
    const float* __restrict__ key, const float* __restrict__ q,
    float* __restrict__ wsc) {
  int l = threadIdx.x;
  float qv = q[l];
  float d[4];
#pragma unroll
  for (int m = 0; m < 4; ++m) {
    float p = qv * key[m * 64 + l];
#pragma unroll
    for (int off = 32; off; off >>= 1) p += __shfl_xor(p, off, 64);
    d[m] = p * (1.0f / NN);  // mean over nodes
  }
  if (l == 0) {
    {
      float mx = fmaxf(d[1], d[2]);
      float e1 = __expf(d[1] - mx), e2 = __expf(d[2] - mx);
      float inv = 1.f / (e1 + e2);
      wsc[1] = e1 * inv;
      wsc[2] = e2 * inv;
    }
    {
      float mx = fmaxf(d[0], d[3]);
      float e0 = __expf(d[0] - mx), e3 = __expf(d[3] - mx);
      float inv = 1.f / (e0 + e3);
      wsc[0] = e0 * inv;
      wsc[3] = e3 * inv;
    }
  }
}

__global__ __launch_bounds__(256) void combine_kernel(
    const float* __restrict__ out_et, const float* __restrict__ wsc,
    float* __restrict__ out) {
  size_t i4 = (size_t)blockIdx.x * 256 + threadIdx.x;  // float4 index over [2][N][16]
  if (i4 >= (size_t)2 * NN * 16) return;
  int type = i4 >= (size_t)NN * 16;
  size_t r4 = type ? i4 - (size_t)NN * 16 : i4;
  int m0 = type ? 0 : 1;
  int m1 = type ? 3 : 2;
  float s0 = wsc[m0], s1 = wsc[m1];
  f4 a = __builtin_nontemporal_load((const f4*)out_et + (size_t)m0 * NN * 16 + r4);
  f4 b = __builtin_nontemporal_load((const f4*)out_et + (size_t)m1 * NN * 16 + r4);
  float4 o;
  o.x = s0 * a.x + s1 * b.x;
  o.y = s0 * a.y + s1 * b.y;
  o.z = s0 * a.z + s1 * b.z;
  o.w = s0 * a.w + s1 * b.w;
  ((float4*)out)[i4] = o;
}

// ---------------------------------------------------------------------------
extern "C" void kernel_launch(void* const* d_in, const int* in_sizes, int n_in,
                              void* d_out, int out_size, void* d_ws,
                              size_t ws_size, hipStream_t stream) {
  const float* x_a = (const float*)d_in[0];
  const float* x_p = (const float*)d_in[1];
  const int* ei0 = (const int*)d_in[2];   // a->p
  const int* ei1 = (const int*)d_in[3];   // p->a
  const int* ei2 = (const int*)d_in[4];   // a->a
  const int* ei3 = (const int*)d_in[5];   // p->p
  const float* Wfa = (const float*)d_in[6];
  const float* bfa = (const float*)d_in[7];
  const float* Wfp = (const float*)d_in[8];
  const float* bfp = (const float*)d_in[9];
  const float* gWs = (const float*)d_in[10];
  const float* gWd = (const float*)d_in[11];
  const float* gas = (const float*)d_in[12];
  const float* gad = (const float*)d_in[13];
  const float* gb = (const float*)d_in[14];
  const float* Wk = (const float*)d_in[15];
  const float* bk = (const float*)d_in[16];
  const float* q = (const float*)d_in[17];
  float* out = (float*)d_out;
  (void)in_sizes; (void)n_in; (void)out_size; (void)ws_size;

  float* ws = (float*)d_ws;
  float* h = ws;                                     // 2*N*8
  float* out_et = h + (size_t)2 * NN * 8;            // 4*N*64
  float* Vs = out_et + (size_t)4 * NN * 64;          // 256
  float* Vd = Vs + 256;                              // 256
  float* key = Vd + 256;                             // 256
  float* wsc = key + 256;                            // 8 (4 used)
  int* counts = (int*)(wsc + 8);                     // 4*N
  int* rowptr = counts + (size_t)4 * NN;             // 4*N
  int* gcur = rowptr + (size_t)4 * NN;               // 4*NBUK (pad 1024)
  int* edge_src = gcur + 1024;                       // 4*NBUK*CAP ints

  hipMemsetAsync(gcur, 0, 1024 * sizeof(int), stream);
  hipMemsetAsync(key, 0, 256 * sizeof(float), stream);

  prep_V<<<1, 512, 0, stream>>>(gWs, gas, gWd, gad, Vs, Vd);
  fc_kernel<<<2 * NODEBLK, 256, 0, stream>>>(x_a, x_p, Wfa, bfa, Wfp, bfp, h);
  bin_kernel<<<dim3(BINBLK, 4), 256, 0, stream>>>(ei0, ei1, ei2, ei3, gcur, edge_src);
  csr_kernel<<<dim3(NBUK, 4), 256, 0, stream>>>(gcur, edge_src, counts, rowptr);
  gat_pull<<<1568, 256, 0, stream>>>(h, rowptr, counts, edge_src,
                                     gWs, Vs, Vd, gb, out_et);
  semantic_key<<<dim3(256, 4), 256, 0, stream>>>(out_et, Wk, bk, key);
  scores_k<<<1, 64, 0, stream>>>(key, q, wsc);
  combine_kernel<<<(2 * NN * 16 + 255) / 256, 256, 0, stream>>>(out_et, wsc, out);
}